// Round 1
// baseline (527.922 us; speedup 1.0000x reference)
//
#include <hip/hip_runtime.h>
#include <stdint.h>

typedef unsigned short ushort_t;
typedef unsigned int uint_t;
typedef __bf16 bf16x8 __attribute__((ext_vector_type(8)));
typedef float f32x4 __attribute__((ext_vector_type(4)));

#define GLOBAL_AS __attribute__((address_space(1)))
#define LDS_AS    __attribute__((address_space(3)))

#define SCALE_CONV 0.014731391f   /* 1/sqrt(512*9) */
#define SCALE_RGB  0.044194174f   /* 1/sqrt(512)   */
#define SQRT2_F    1.41421356237f

// ---------------------------------------------------------------- helpers
__device__ __forceinline__ void async_cp16(const void* g, void* l) {
  __builtin_amdgcn_global_load_lds((const GLOBAL_AS uint_t*)g,
                                   (LDS_AS uint_t*)l, 16, 0, 0);
}
__device__ __forceinline__ ushort_t f2bf(float v) {
  union { float f; uint_t u; } c; c.f = v;
  uint_t r = c.u + 0x7fffu + ((c.u >> 16) & 1u);   // RNE
  return (ushort_t)(r >> 16);
}
__device__ __forceinline__ float bf2f(ushort_t u) {
  union { uint_t u; float f; } c; c.u = ((uint_t)u) << 16;
  return c.f;
}

// ------------------------------------------------- prep: x -> xpad1 (NHWC bf16, pad1, *s1*scale)
__global__ __launch_bounds__(256) void prep_x1(
    const float* __restrict__ x, const float* __restrict__ s1,
    ushort_t* __restrict__ xpad) {
  __shared__ ushort_t t[32 * 520];
  const int b  = blockIdx.x >> 5;
  const int j1 = blockIdx.x & 31;
  for (int idx = threadIdx.x; idx < 512 * 32; idx += 256) {
    int ci = idx >> 5, j2 = idx & 31;
    float v = x[(size_t)(b * 512 + ci) * 1024 + j1 * 32 + j2];
    v *= s1[b * 512 + ci] * SCALE_CONV;
    t[j2 * 520 + ci] = f2bf(v);
  }
  __syncthreads();
  for (int idx = threadIdx.x; idx < 32 * 512; idx += 256) {
    int j2 = idx >> 9, ci = idx & 511;
    xpad[((size_t)(b * 34 + j1 + 1) * 34 + (j2 + 1)) * 512 + ci] = t[j2 * 520 + ci];
  }
}

// ------------------------------------------------- prep: w1 -> blur-fused phase weights wt1[a][co][tap][ci]
__constant__ float c1tab[2][3][3] = {
  {{0.f, .25f, .75f}, {.75f, .75f, .25f}, {.25f, 0.f, 0.f}},   // even output phase
  {{0.f, 0.f, .25f}, {.25f, .75f, .75f}, {.75f, .25f, 0.f}}    // odd output phase
};

__global__ __launch_bounds__(256) void prep_w1(
    const float* __restrict__ w1, ushort_t* __restrict__ wt1) {
  int t = blockIdx.x * 256 + threadIdx.x;       // 4*512*512
  int ci = t & 511, co = (t >> 9) & 511, a = t >> 18;
  int a1 = a >> 1, a2 = a & 1;
  float w[3][3];
  const float* wp = w1 + (size_t)(co * 512 + ci) * 9;
#pragma unroll
  for (int u = 0; u < 9; ++u) w[u / 3][u % 3] = wp[u];
#pragma unroll
  for (int djy = 0; djy < 3; ++djy)
#pragma unroll
    for (int dkx = 0; dkx < 3; ++dkx) {
      float g = 0.f;
#pragma unroll
      for (int u1 = 0; u1 < 3; ++u1)
#pragma unroll
        for (int u2 = 0; u2 < 3; ++u2)
          g += w[u1][u2] * c1tab[a1][djy][u1] * c1tab[a2][dkx][u2];
      wt1[((size_t)(a * 512 + co) * 9 + djy * 3 + dkx) * 512 + ci] = f2bf(g);
    }
}

// ------------------------------------------------- prep: w2 -> wt2[co][tap][ci] bf16
__global__ __launch_bounds__(256) void prep_w2(
    const float* __restrict__ w2, ushort_t* __restrict__ wt2) {
  int t = blockIdx.x * 256 + threadIdx.x;       // 512*512
  int ci = t & 511, co = t >> 9;
  const float* wp = w2 + (size_t)(co * 512 + ci) * 9;
#pragma unroll
  for (int u = 0; u < 9; ++u)
    wt2[((size_t)co * 9 + u) * 512 + ci] = f2bf(wp[u]);
}

// ------------------------------------------------- demod factors d[b][co]
__global__ __launch_bounds__(256) void demod_k(
    const float* __restrict__ w1, const float* __restrict__ s1, float* __restrict__ d1,
    const float* __restrict__ w2, const float* __restrict__ s2, float* __restrict__ d2) {
  const int co = blockIdx.x, b = blockIdx.y;
  const float* w = blockIdx.z ? w2 : w1;
  const float* s = blockIdx.z ? s2 : s1;
  float*       d = blockIdx.z ? d2 : d1;
  float acc = 0.f;
  for (int ci = threadIdx.x; ci < 512; ci += 256) {
    const float* wp = w + (size_t)(co * 512 + ci) * 9;
    float ws = 0.f;
#pragma unroll
    for (int u = 0; u < 9; ++u) ws += wp[u] * wp[u];
    float sv = s[b * 512 + ci];
    acc += ws * sv * sv;
  }
#pragma unroll
  for (int o = 32; o; o >>= 1) acc += __shfl_xor(acc, o);
  __shared__ float red[4];
  if ((threadIdx.x & 63) == 0) red[threadIdx.x >> 6] = acc;
  __syncthreads();
  if (threadIdx.x == 0) {
    float tot = red[0] + red[1] + red[2] + red[3];
    d[b * 512 + co] = rsqrtf(tot * (1.f / 4608.f) + 1e-8f);
  }
}

// ------------------------------------------------- main implicit-GEMM conv (conv1 phases / conv2)
// CONV1: input xpad1 [8][34][34][512], grid (64,4,4); output out1pad [8][66][66][512] (strided phase write)
// CONV2: input out1pad [8][66][66][512], grid (256,4,1); output out2s [8][64][64][512]
template <bool CONV1>
__global__ __launch_bounds__(256, 3) void gemm_conv(
    const ushort_t* __restrict__ inp, const ushort_t* __restrict__ wt,
    const float* __restrict__ dmod, const float* __restrict__ noise,
    const float* __restrict__ nw, const float* __restrict__ bias,
    const float* __restrict__ snext, float snext_scale,
    ushort_t* __restrict__ outp) {
  constexpr int WP = CONV1 ? 34 : 66;
  __shared__ ushort_t ldsA[128 * 32];
  __shared__ ushort_t ldsB[128 * 32];

  const int tid  = threadIdx.x;
  const int lane = tid & 63;
  const int wv   = tid >> 6;
  const int wm   = wv & 1;
  const int wn   = wv >> 1;
  const int l16  = lane & 15;
  const int quad = lane >> 4;

  const int mtile = blockIdx.x;
  const int ntile = blockIdx.y;
  const int a  = CONV1 ? blockIdx.z : 0;
  const int a1 = a >> 1, a2 = a & 1;
  const int b  = CONV1 ? (mtile >> 3) : (mtile >> 5);

  // ---- staging lane constants (XOR-swizzled LDS layout at 16B granularity)
  const int ql = (lane & 3) ^ ((lane >> 2) & 3);
  const char* pA[2];
  const char* pB[2];
#pragma unroll
  for (int t = 0; t < 2; ++t) {
    int ml = wv * 32 + t * 16 + (lane >> 2);
    int m  = mtile * 128 + ml;
    int y0, x0;
    if (CONV1) { y0 = ((m >> 5) & 31) + 1; x0 = (m & 31) + 1; }
    else       { y0 = ((m >> 6) & 63) + 1; x0 = (m & 63) + 1; }
    size_t pix = ((size_t)(b * WP + y0) * WP + x0) * 512;
    pA[t] = (const char*)inp + pix * 2 + ql * 16;
    int n = ntile * 128 + ml;
    size_t wb = ((size_t)(a * 512 + n) * 9) * 512;
    pB[t] = (const char*)wt + wb * 2 + ql * 16;
  }
  char* ldsAdst[2];
  char* ldsBdst[2];
#pragma unroll
  for (int t = 0; t < 2; ++t) {
    ldsAdst[t] = (char*)ldsA + (wv * 128 + t * 64) * 16;
    ldsBdst[t] = (char*)ldsB + (wv * 128 + t * 64) * 16;
  }

  // ---- MFMA fragment LDS offsets (ushort units), same swizzle
  const int q2 = quad ^ (lane & 3);
  int offA[4], offB[4];
#pragma unroll
  for (int i = 0; i < 4; ++i) {
    offA[i] = ((wm * 64 + i * 16 + l16) * 4 + q2) * 8;
    offB[i] = ((wn * 64 + i * 16 + l16) * 4 + q2) * 8;
  }

  f32x4 acc[4][4];
#pragma unroll
  for (int i = 0; i < 4; ++i)
#pragma unroll
    for (int j = 0; j < 4; ++j) acc[i][j] = (f32x4){0.f, 0.f, 0.f, 0.f};

#pragma unroll 1
  for (int tap = 0; tap < 9; ++tap) {
    const int dj = tap / 3 - 1, dk = tap % 3 - 1;
    const int aoff = (dj * WP + dk) * 1024;   // bytes (512ch * 2B)
    const int boff = tap * 1024;
#pragma unroll 1
    for (int kc = 0; kc < 16; ++kc) {
      const int koff = kc * 64;
      __syncthreads();
      async_cp16(pA[0] + aoff + koff, ldsAdst[0]);
      async_cp16(pA[1] + aoff + koff, ldsAdst[1]);
      async_cp16(pB[0] + boff + koff, ldsBdst[0]);
      async_cp16(pB[1] + boff + koff, ldsBdst[1]);
      __syncthreads();
      bf16x8 af[4], bg[4];
#pragma unroll
      for (int i = 0; i < 4; ++i) af[i] = *reinterpret_cast<const bf16x8*>(ldsA + offA[i]);
#pragma unroll
      for (int j = 0; j < 4; ++j) bg[j] = *reinterpret_cast<const bf16x8*>(ldsB + offB[j]);
#pragma unroll
      for (int i = 0; i < 4; ++i)
#pragma unroll
        for (int j = 0; j < 4; ++j)
          acc[i][j] = __builtin_amdgcn_mfma_f32_16x16x32_bf16(af[i], bg[j], acc[i][j], 0, 0, 0);
    }
  }

  // ---- epilogue: demod + noise + bias + lrelu*sqrt2 + next-layer style scale -> bf16 NHWC
  const float nwv = nw[0];
  float dj_[4], sj_[4], bj_[4];
  int co_[4];
#pragma unroll
  for (int j = 0; j < 4; ++j) {
    int co = ntile * 128 + wn * 64 + j * 16 + l16;
    co_[j] = co;
    dj_[j] = dmod[b * 512 + co];
    sj_[j] = snext[b * 512 + co] * snext_scale;
    bj_[j] = bias[co];
  }
#pragma unroll
  for (int i = 0; i < 4; ++i) {
#pragma unroll
    for (int r = 0; r < 4; ++r) {
      int m = mtile * 128 + wm * 64 + i * 16 + quad * 4 + r;
      int o1, o2;
      if (CONV1) { o1 = 2 * ((m >> 5) & 31) + a1; o2 = 2 * (m & 31) + a2; }
      else       { o1 = (m >> 6) & 63;            o2 = m & 63; }
      float nz = nwv * noise[(b << 12) + (o1 << 6) + o2];
      size_t ob;
      if (CONV1) ob = ((size_t)(b * 66 + o1 + 1) * 66 + (o2 + 1)) * 512;
      else       ob = ((size_t)(b * 64 + o1) * 64 + o2) * 512;
#pragma unroll
      for (int j = 0; j < 4; ++j) {
        float v = acc[i][j][r] * dj_[j] + nz + bj_[j];
        v = (v >= 0.f ? v : 0.2f * v) * SQRT2_F;
        v *= sj_[j];
        outp[ob + co_[j]] = f2bf(v);
      }
    }
  }
}

// ------------------------------------------------- ToRGB (1x1, no demod) + bias + skip upfirdn(up=2)
__global__ __launch_bounds__(256) void torgb_skip(
    const ushort_t* __restrict__ out2s, const float* __restrict__ wrgb,
    const float* __restrict__ brgb, const float* __restrict__ skip,
    float* __restrict__ out) {
  const int lane = threadIdx.x & 63;
  const int pix  = blockIdx.x * 4 + (threadIdx.x >> 6);   // 32768 pixels
  const int b = pix >> 12, o1 = (pix >> 6) & 63, o2 = pix & 63;
  const ushort_t* src = out2s + (size_t)pix * 512 + lane * 8;
  ushort_t v[8];
  *(uint4*)v = *(const uint4*)src;
  float s0 = 0.f, s1 = 0.f, s2 = 0.f;
#pragma unroll
  for (int e = 0; e < 8; ++e) {
    float xv = bf2f(v[e]);
    int ci = lane * 8 + e;
    s0 += xv * wrgb[ci];
    s1 += xv * wrgb[512 + ci];
    s2 += xv * wrgb[1024 + ci];
  }
#pragma unroll
  for (int o = 32; o; o >>= 1) {
    s0 += __shfl_xor(s0, o);
    s1 += __shfl_xor(s1, o);
    s2 += __shfl_xor(s2, o);
  }
  if (lane < 3) {
    float v3 = (lane == 0) ? s0 : (lane == 1 ? s1 : s2);
    int P1 = o1 >> 1, P2 = o2 >> 1;
    int jy0, jy1, jx0, jx1;
    float wy0, wy1, wx0, wx1;
    if ((o1 & 1) == 0) { jy0 = P1 - 1; wy0 = .25f; jy1 = P1;     wy1 = .75f; }
    else               { jy0 = P1;     wy0 = .75f; jy1 = P1 + 1; wy1 = .25f; }
    if ((o2 & 1) == 0) { jx0 = P2 - 1; wx0 = .25f; jx1 = P2;     wx1 = .75f; }
    else               { jx0 = P2;     wx0 = .75f; jx1 = P2 + 1; wx1 = .25f; }
    const float* sp = skip + (size_t)(b * 3 + lane) * 1024;
    float sv = 0.f;
    if (jy0 >= 0 && jy0 < 32) {
      if (jx0 >= 0 && jx0 < 32) sv += wy0 * wx0 * sp[jy0 * 32 + jx0];
      if (jx1 >= 0 && jx1 < 32) sv += wy0 * wx1 * sp[jy0 * 32 + jx1];
    }
    if (jy1 >= 0 && jy1 < 32) {
      if (jx0 >= 0 && jx0 < 32) sv += wy1 * wx0 * sp[jy1 * 32 + jx0];
      if (jx1 >= 0 && jx1 < 32) sv += wy1 * wx1 * sp[jy1 * 32 + jx1];
    }
    out[((size_t)(b * 3 + lane) << 12) + (o1 << 6) + o2] = v3 + brgb[lane] + sv;
  }
}

// ------------------------------------------------- launch
extern "C" void kernel_launch(void* const* d_in, const int* in_sizes, int n_in,
                              void* d_out, int out_size, void* d_ws, size_t ws_size,
                              hipStream_t stream) {
  const float* x    = (const float*)d_in[0];
  const float* skip = (const float*)d_in[1];
  const float* w1   = (const float*)d_in[2];
  const float* b1   = (const float*)d_in[3];
  const float* s1   = (const float*)d_in[4];
  const float* nw1  = (const float*)d_in[5];
  const float* n1   = (const float*)d_in[6];
  const float* w2   = (const float*)d_in[7];
  const float* b2   = (const float*)d_in[8];
  const float* s2   = (const float*)d_in[9];
  const float* nw2  = (const float*)d_in[10];
  const float* n2   = (const float*)d_in[11];
  const float* wrgb = (const float*)d_in[12];
  const float* brgb = (const float*)d_in[13];
  const float* srgb = (const float*)d_in[14];

  char* ws = (char*)d_ws;
  const size_t XPAD_B = (size_t)8 * 34 * 34 * 512 * 2;   //  9,469,952
  const size_t OUT1_B = (size_t)8 * 66 * 66 * 512 * 2;   // 35,684,352
  const size_t OUT2_B = (size_t)8 * 64 * 64 * 512 * 2;   // 33,554,432
  const size_t WT1_B  = (size_t)4 * 512 * 9 * 512 * 2;   // 18,874,368
  const size_t WT2_B  = (size_t)512 * 9 * 512 * 2;       //  4,718,592
  size_t off = 0;
  ushort_t* xpad1   = (ushort_t*)(ws + off); off += XPAD_B;
  ushort_t* out1pad = (ushort_t*)(ws + off); off += OUT1_B;
  ushort_t* out2s   = (ushort_t*)(ws + off); off += OUT2_B;
  ushort_t* wt1     = (ushort_t*)(ws + off); off += WT1_B;
  ushort_t* wt2     = (ushort_t*)(ws + off); off += WT2_B;
  float*    d1      = (float*)(ws + off);    off += 8 * 512 * 4;
  float*    d2      = (float*)(ws + off);    off += 8 * 512 * 4;

  // zero padded borders (whole buffers; interiors get overwritten)
  hipMemsetAsync(xpad1, 0, XPAD_B, stream);
  hipMemsetAsync(out1pad, 0, OUT1_B, stream);

  prep_x1<<<256, 256, 0, stream>>>(x, s1, xpad1);
  prep_w1<<<4096, 256, 0, stream>>>(w1, wt1);
  prep_w2<<<1024, 256, 0, stream>>>(w2, wt2);
  demod_k<<<dim3(512, 8, 2), 256, 0, stream>>>(w1, s1, d1, w2, s2, d2);

  // conv1 (blur-fused upsampling modulated conv), 4 phases
  gemm_conv<true><<<dim3(64, 4, 4), 256, 0, stream>>>(
      xpad1, wt1, d1, n1, nw1, b1, s2, SCALE_CONV, out1pad);
  // conv2 (plain modulated conv)
  gemm_conv<false><<<dim3(256, 4, 1), 256, 0, stream>>>(
      out1pad, wt2, d2, n2, nw2, b2, srgb, SCALE_RGB, out2s);
  // ToRGB + skip upsample
  torgb_skip<<<8192, 256, 0, stream>>>(out2s, wrgb, brgb, skip, (float*)d_out);
}

// Round 2
// 406.081 us; speedup vs baseline: 1.3000x; 1.3000x over previous
//
#include <hip/hip_runtime.h>
#include <stdint.h>

typedef unsigned short ushort_t;
typedef unsigned int uint_t;
typedef __bf16 bf16x8 __attribute__((ext_vector_type(8)));
typedef float f32x4 __attribute__((ext_vector_type(4)));

#define GLOBAL_AS __attribute__((address_space(1)))
#define LDS_AS    __attribute__((address_space(3)))

#define SCALE_CONV 0.014731391f   /* 1/sqrt(512*9) */
#define SCALE_RGB  0.044194174f   /* 1/sqrt(512)   */
#define SQRT2_F    1.41421356237f

// ---------------------------------------------------------------- helpers
__device__ __forceinline__ void async_cp16(const void* g, void* l) {
  __builtin_amdgcn_global_load_lds((const GLOBAL_AS uint_t*)g,
                                   (LDS_AS uint_t*)l, 16, 0, 0);
}
__device__ __forceinline__ ushort_t f2bf(float v) {
  union { float f; uint_t u; } c; c.f = v;
  uint_t r = c.u + 0x7fffu + ((c.u >> 16) & 1u);   // RNE
  return (ushort_t)(r >> 16);
}
__device__ __forceinline__ float bf2f(ushort_t u) {
  union { uint_t u; float f; } c; c.u = ((uint_t)u) << 16;
  return c.f;
}

// ------------------------------------------------- prep: x -> xpad1 (NHWC bf16, pad1, *s1*scale)
__global__ __launch_bounds__(256) void prep_x1(
    const float* __restrict__ x, const float* __restrict__ s1,
    ushort_t* __restrict__ xpad) {
  __shared__ ushort_t t[32 * 520];
  const int b  = blockIdx.x >> 5;
  const int j1 = blockIdx.x & 31;
  for (int idx = threadIdx.x; idx < 512 * 32; idx += 256) {
    int ci = idx >> 5, j2 = idx & 31;
    float v = x[(size_t)(b * 512 + ci) * 1024 + j1 * 32 + j2];
    v *= s1[b * 512 + ci] * SCALE_CONV;
    t[j2 * 520 + ci] = f2bf(v);
  }
  __syncthreads();
  for (int idx = threadIdx.x; idx < 32 * 512; idx += 256) {
    int j2 = idx >> 9, ci = idx & 511;
    xpad[((size_t)(b * 34 + j1 + 1) * 34 + (j2 + 1)) * 512 + ci] = t[j2 * 520 + ci];
  }
}

// ------------------------------------------------- prep: w -> wt[plane][co][ci] bf16 (pure transpose)
__global__ __launch_bounds__(256) void prep_w(
    const float* __restrict__ w, ushort_t* __restrict__ wt) {
  int t = blockIdx.x * 256 + threadIdx.x;       // 512*512
  int ci = t & 511, co = t >> 9;
  const float* wp = w + (size_t)(co * 512 + ci) * 9;
#pragma unroll
  for (int u = 0; u < 9; ++u)
    wt[((size_t)u * 512 + co) * 512 + ci] = f2bf(wp[u]);
}

// ------------------------------------------------- demod factors d[b][co]
__global__ __launch_bounds__(256) void demod_k(
    const float* __restrict__ w1, const float* __restrict__ s1, float* __restrict__ d1,
    const float* __restrict__ w2, const float* __restrict__ s2, float* __restrict__ d2) {
  const int co = blockIdx.x, b = blockIdx.y;
  const float* w = blockIdx.z ? w2 : w1;
  const float* s = blockIdx.z ? s2 : s1;
  float*       d = blockIdx.z ? d2 : d1;
  float acc = 0.f;
  for (int ci = threadIdx.x; ci < 512; ci += 256) {
    const float* wp = w + (size_t)(co * 512 + ci) * 9;
    float ws = 0.f;
#pragma unroll
    for (int u = 0; u < 9; ++u) ws += wp[u] * wp[u];
    float sv = s[b * 512 + ci];
    acc += ws * sv * sv;
  }
#pragma unroll
  for (int o = 32; o; o >>= 1) acc += __shfl_xor(acc, o);
  __shared__ float red[4];
  if ((threadIdx.x & 63) == 0) red[threadIdx.x >> 6] = acc;
  __syncthreads();
  if (threadIdx.x == 0) {
    float tot = red[0] + red[1] + red[2] + red[3];
    d[b * 512 + co] = rsqrtf(tot * (1.f / 4608.f) + 1e-8f);
  }
}

// ------------------------------------------------- conv1 phase tap tables (convT stride-2, k=3)
// phase a=(a1,a2): out[2p+a] = sum over taps; a=0 dims use u in {0,1} with ky=g(u) (g(0)=2,g(1)=0),
// a=1 dims use u=1 with ky=1. Input row = xpad[p+u].
__constant__ int           c_ph_off[4]  = {0, 4, 6, 8};
__constant__ int           c_ph_ntap[4] = {4, 2, 2, 1};
__constant__ unsigned char c_tap_u1[9]  = {0,0,1,1, 0,1, 1,1, 1};
__constant__ unsigned char c_tap_u2[9]  = {0,1,0,1, 1,1, 0,1, 1};
__constant__ unsigned char c_tap_pl[9]  = {8,6,2,0, 7,1, 5,3, 4};

// ------------------------------------------------- main implicit-GEMM conv
// MODE 0: conv1 phase GEMM. input xpad1 [8][34][34][512]; grid (69,4,4); M=8*33*33=8712 per phase;
//         output y1pad [8][67][67][512] (raw conv * demod, bf16)
// MODE 1: conv2. input out1pad [8][66][66][512]; grid (256,4,1); output out2s [8][64][64][512]
template <int MODE>
__global__ __launch_bounds__(256, 4) void gemm_conv(
    const ushort_t* __restrict__ inp, const ushort_t* __restrict__ wt,
    const float* __restrict__ dmod, const float* __restrict__ noise,
    const float* __restrict__ nw, const float* __restrict__ bias,
    const float* __restrict__ snext, float snext_scale,
    ushort_t* __restrict__ outp) {
  __shared__ ushort_t ldsA[128 * 32];
  __shared__ ushort_t ldsB[128 * 32];

  const int tid  = threadIdx.x;
  const int lane = tid & 63;
  const int wv   = tid >> 6;
  const int wm   = wv & 1;
  const int wn   = wv >> 1;
  const int l16  = lane & 15;
  const int quad = lane >> 4;

  const int mtile = blockIdx.x;
  const int ntile = blockIdx.y;
  const int a  = (MODE == 0) ? blockIdx.z : 0;
  const int a1 = a >> 1, a2 = a & 1;

  // ---- staging lane constants.
  // LDS layout swizzle: chunk position within a 4-chunk (64B) row for global k-quad c is
  // pos = (c + (row>>1)) & 3  -> ds_read_b128 chunk index mod 8 is a permutation over every
  // 8 consecutive lanes (bank-conflict free). Staging lane fetches k-quad ((lane&3)-(lane>>3))&3.
  const int qg = ((lane & 3) - (lane >> 3)) & 3;
  const char* pA[2];
  const char* pB[2];
#pragma unroll
  for (int t = 0; t < 2; ++t) {
    int row = wv * 32 + t * 16 + (lane >> 2);
    int m   = mtile * 128 + row;
    size_t pix;
    if (MODE == 0) {
      if (m > 8711) m = 8711;
      int b = m / 1089, rr = m % 1089;
      int p1 = rr / 33, p2 = rr % 33;
      pix = ((size_t)(b * 34 + p1) * 34 + p2) * 512;
    } else {
      int b = m >> 12, o1 = (m >> 6) & 63, o2 = m & 63;
      pix = ((size_t)(b * 66 + o1 + 1) * 66 + (o2 + 1)) * 512;
    }
    pA[t] = (const char*)inp + pix * 2 + qg * 16;
    int n = ntile * 128 + row;
    pB[t] = (const char*)wt + (size_t)n * 1024 + qg * 16;
  }
  char* ldsAdst[2];
  char* ldsBdst[2];
#pragma unroll
  for (int t = 0; t < 2; ++t) {
    ldsAdst[t] = (char*)ldsA + (wv * 128 + t * 64) * 16;
    ldsBdst[t] = (char*)ldsB + (wv * 128 + t * 64) * 16;
  }

  // ---- MFMA fragment LDS offsets (ushort units), same swizzle
  int offA[4], offB[4];
#pragma unroll
  for (int i = 0; i < 4; ++i) {
    int r  = wm * 64 + i * 16 + l16;
    int rn = wn * 64 + i * 16 + l16;
    offA[i] = r  * 32 + (((quad + (r  >> 1)) & 3) << 3);
    offB[i] = rn * 32 + (((quad + (rn >> 1)) & 3) << 3);
  }

  f32x4 acc[4][4];
#pragma unroll
  for (int i = 0; i < 4; ++i)
#pragma unroll
    for (int j = 0; j < 4; ++j) acc[i][j] = (f32x4){0.f, 0.f, 0.f, 0.f};

  const int ntap = (MODE == 0) ? c_ph_ntap[a] : 9;
#pragma unroll 1
  for (int ti = 0; ti < ntap; ++ti) {
    int aoff, boff;
    if (MODE == 0) {
      int e = c_ph_off[a] + ti;
      aoff = ((int)c_tap_u1[e] * 34 + (int)c_tap_u2[e]) * 1024;
      boff = (int)c_tap_pl[e] * 524288;
    } else {
      aoff = ((ti / 3 - 1) * 66 + (ti % 3 - 1)) * 1024;
      boff = ti * 524288;
    }
#pragma unroll 1
    for (int kc = 0; kc < 16; ++kc) {
      const int koff = kc * 64;
      __syncthreads();
      async_cp16(pA[0] + aoff + koff, ldsAdst[0]);
      async_cp16(pA[1] + aoff + koff, ldsAdst[1]);
      async_cp16(pB[0] + boff + koff, ldsBdst[0]);
      async_cp16(pB[1] + boff + koff, ldsBdst[1]);
      __syncthreads();
      bf16x8 af[4], bg[4];
#pragma unroll
      for (int i = 0; i < 4; ++i) af[i] = *reinterpret_cast<const bf16x8*>(ldsA + offA[i]);
#pragma unroll
      for (int j = 0; j < 4; ++j) bg[j] = *reinterpret_cast<const bf16x8*>(ldsB + offB[j]);
#pragma unroll
      for (int i = 0; i < 4; ++i)
#pragma unroll
        for (int j = 0; j < 4; ++j)
          acc[i][j] = __builtin_amdgcn_mfma_f32_16x16x32_bf16(af[i], bg[j], acc[i][j], 0, 0, 0);
    }
  }

  // ---- epilogue
  int co_[4];
#pragma unroll
  for (int j = 0; j < 4; ++j) co_[j] = ntile * 128 + wn * 64 + j * 16 + l16;

  if (MODE == 0) {
    // raw conv output * demod -> y1pad (blur/noise/act happen in the blur pass)
#pragma unroll
    for (int i = 0; i < 4; ++i) {
#pragma unroll
      for (int r = 0; r < 4; ++r) {
        int m = mtile * 128 + wm * 64 + i * 16 + quad * 4 + r;
        if (m < 8712) {
          int b = m / 1089, rr = m % 1089;
          int p1 = rr / 33, p2 = rr % 33;
          if ((a1 == 0 || p1 < 32) && (a2 == 0 || p2 < 32)) {
            int o1 = 2 * p1 + a1, o2 = 2 * p2 + a2;
            size_t ob = ((size_t)(b * 67 + o1 + 1) * 67 + (o2 + 1)) * 512;
#pragma unroll
            for (int j = 0; j < 4; ++j)
              outp[ob + co_[j]] = f2bf(acc[i][j][r] * dmod[b * 512 + co_[j]]);
          }
        }
      }
    }
  } else {
    const int b = mtile >> 5;
    const float nwv = nw[0];
    float dj_[4], sj_[4], bj_[4];
#pragma unroll
    for (int j = 0; j < 4; ++j) {
      dj_[j] = dmod[b * 512 + co_[j]];
      sj_[j] = snext[b * 512 + co_[j]] * snext_scale;
      bj_[j] = bias[co_[j]];
    }
#pragma unroll
    for (int i = 0; i < 4; ++i) {
#pragma unroll
      for (int r = 0; r < 4; ++r) {
        int m = mtile * 128 + wm * 64 + i * 16 + quad * 4 + r;
        int o1 = (m >> 6) & 63, o2 = m & 63;
        float nz = nwv * noise[(b << 12) + (o1 << 6) + o2];
        size_t ob = ((size_t)(b * 64 + o1) * 64 + o2) * 512;
#pragma unroll
        for (int j = 0; j < 4; ++j) {
          float v = acc[i][j][r] * dj_[j] + nz + bj_[j];
          v = (v >= 0.f ? v : 0.2f * v) * SQRT2_F;
          v *= sj_[j];
          outp[ob + co_[j]] = f2bf(v);
        }
      }
    }
  }
}

// ------------------------------------------------- blur(4-tap separable) + noise + bias + lrelu + s2-scale
// y1pad [8][67][67][512] -> out1pad [8][66][66][512] (interior [1..64])
__global__ __launch_bounds__(256) void blur_noise_act(
    const ushort_t* __restrict__ y1pad, const float* __restrict__ noise,
    const float* __restrict__ nw, const float* __restrict__ bias,
    const float* __restrict__ s2, ushort_t* __restrict__ out1pad) {
  const int cg  = threadIdx.x & 63;                       // channel octet
  const int pg  = blockIdx.x * 4 + (threadIdx.x >> 6);    // 0..8191
  const int b   = pg >> 10;
  const int q1  = (pg >> 4) & 63;
  const int q2g = (pg & 15) * 4;                          // 4 consecutive output cols
  const float cw[4] = {0.25f, 0.75f, 0.75f, 0.25f};

  float acc[4][8];
#pragma unroll
  for (int j = 0; j < 4; ++j)
#pragma unroll
    for (int e = 0; e < 8; ++e) acc[j][e] = 0.f;

#pragma unroll
  for (int t2 = 0; t2 < 7; ++t2) {
    int cc = q2g + t2;
    float vt[8];
#pragma unroll
    for (int e = 0; e < 8; ++e) vt[e] = 0.f;
#pragma unroll
    for (int t1 = 0; t1 < 4; ++t1) {
      const ushort_t* p = y1pad + ((size_t)(b * 67 + q1 + t1) * 67 + cc) * 512 + cg * 8;
      ushort_t v[8];
      *(uint4*)v = *(const uint4*)p;
#pragma unroll
      for (int e = 0; e < 8; ++e) vt[e] += cw[t1] * bf2f(v[e]);
    }
#pragma unroll
    for (int j = 0; j < 4; ++j) {
      int t = t2 - j;
      if (t >= 0 && t < 4) {
#pragma unroll
        for (int e = 0; e < 8; ++e) acc[j][e] += cw[t] * vt[e];
      }
    }
  }

  const float nwv = nw[0];
  float bj[8], sj[8];
#pragma unroll
  for (int e = 0; e < 8; ++e) {
    bj[e] = bias[cg * 8 + e];
    sj[e] = s2[b * 512 + cg * 8 + e] * SCALE_CONV;
  }
#pragma unroll
  for (int j = 0; j < 4; ++j) {
    int q2 = q2g + j;
    float nz = nwv * noise[(b << 12) + (q1 << 6) + q2];
    ushort_t o[8];
#pragma unroll
    for (int e = 0; e < 8; ++e) {
      float v = acc[j][e] + nz + bj[e];
      v = (v >= 0.f ? v : 0.2f * v) * SQRT2_F * sj[e];
      o[e] = f2bf(v);
    }
    *(uint4*)(out1pad + ((size_t)(b * 66 + q1 + 1) * 66 + (q2 + 1)) * 512 + cg * 8) = *(uint4*)o;
  }
}

// ------------------------------------------------- ToRGB (1x1, no demod) + bias + skip upfirdn(up=2)
__global__ __launch_bounds__(256) void torgb_skip(
    const ushort_t* __restrict__ out2s, const float* __restrict__ wrgb,
    const float* __restrict__ brgb, const float* __restrict__ skip,
    float* __restrict__ out) {
  const int lane = threadIdx.x & 63;
  const int pix  = blockIdx.x * 4 + (threadIdx.x >> 6);   // 32768 pixels
  const int b = pix >> 12, o1 = (pix >> 6) & 63, o2 = pix & 63;
  const ushort_t* src = out2s + (size_t)pix * 512 + lane * 8;
  ushort_t v[8];
  *(uint4*)v = *(const uint4*)src;
  float s0 = 0.f, s1 = 0.f, s2 = 0.f;
#pragma unroll
  for (int e = 0; e < 8; ++e) {
    float xv = bf2f(v[e]);
    int ci = lane * 8 + e;
    s0 += xv * wrgb[ci];
    s1 += xv * wrgb[512 + ci];
    s2 += xv * wrgb[1024 + ci];
  }
#pragma unroll
  for (int o = 32; o; o >>= 1) {
    s0 += __shfl_xor(s0, o);
    s1 += __shfl_xor(s1, o);
    s2 += __shfl_xor(s2, o);
  }
  if (lane < 3) {
    float v3 = (lane == 0) ? s0 : (lane == 1 ? s1 : s2);
    int P1 = o1 >> 1, P2 = o2 >> 1;
    int jy0, jy1, jx0, jx1;
    float wy0, wy1, wx0, wx1;
    if ((o1 & 1) == 0) { jy0 = P1 - 1; wy0 = .25f; jy1 = P1;     wy1 = .75f; }
    else               { jy0 = P1;     wy0 = .75f; jy1 = P1 + 1; wy1 = .25f; }
    if ((o2 & 1) == 0) { jx0 = P2 - 1; wx0 = .25f; jx1 = P2;     wx1 = .75f; }
    else               { jx0 = P2;     wx0 = .75f; jx1 = P2 + 1; wx1 = .25f; }
    const float* sp = skip + (size_t)(b * 3 + lane) * 1024;
    float sv = 0.f;
    if (jy0 >= 0 && jy0 < 32) {
      if (jx0 >= 0 && jx0 < 32) sv += wy0 * wx0 * sp[jy0 * 32 + jx0];
      if (jx1 >= 0 && jx1 < 32) sv += wy0 * wx1 * sp[jy0 * 32 + jx1];
    }
    if (jy1 >= 0 && jy1 < 32) {
      if (jx0 >= 0 && jx0 < 32) sv += wy1 * wx0 * sp[jy1 * 32 + jx0];
      if (jx1 >= 0 && jx1 < 32) sv += wy1 * wx1 * sp[jy1 * 32 + jx1];
    }
    out[((size_t)(b * 3 + lane) << 12) + (o1 << 6) + o2] = v3 + brgb[lane] + sv;
  }
}

// ------------------------------------------------- launch
extern "C" void kernel_launch(void* const* d_in, const int* in_sizes, int n_in,
                              void* d_out, int out_size, void* d_ws, size_t ws_size,
                              hipStream_t stream) {
  const float* x    = (const float*)d_in[0];
  const float* skip = (const float*)d_in[1];
  const float* w1   = (const float*)d_in[2];
  const float* b1   = (const float*)d_in[3];
  const float* s1   = (const float*)d_in[4];
  const float* nw1  = (const float*)d_in[5];
  const float* n1   = (const float*)d_in[6];
  const float* w2   = (const float*)d_in[7];
  const float* b2   = (const float*)d_in[8];
  const float* s2   = (const float*)d_in[9];
  const float* nw2  = (const float*)d_in[10];
  const float* n2   = (const float*)d_in[11];
  const float* wrgb = (const float*)d_in[12];
  const float* brgb = (const float*)d_in[13];
  const float* srgb = (const float*)d_in[14];

  char* ws = (char*)d_ws;
  const size_t XPAD_B  = (size_t)8 * 34 * 34 * 512 * 2;   //  9,469,952
  const size_t Y1PAD_B = (size_t)8 * 67 * 67 * 512 * 2;   // 36,773,888
  const size_t OUT1_B  = (size_t)8 * 66 * 66 * 512 * 2;   // 35,684,352
  const size_t WT_B    = (size_t)9 * 512 * 512 * 2;       //  4,718,592
  size_t off = 0;
  ushort_t* xpad1   = (ushort_t*)(ws + off); off += XPAD_B;
  ushort_t* y1pad   = (ushort_t*)(ws + off); off += Y1PAD_B;
  ushort_t* out1pad = (ushort_t*)(ws + off); off += OUT1_B;
  ushort_t* wt1     = (ushort_t*)(ws + off); off += WT_B;
  ushort_t* wt2     = (ushort_t*)(ws + off); off += WT_B;
  float*    d1      = (float*)(ws + off);    off += 8 * 512 * 4;
  float*    d2      = (float*)(ws + off);    off += 8 * 512 * 4;
  // out2s aliases y1pad (y1pad is dead after the blur pass; conv2 writes out2s after blur reads y1pad)
  ushort_t* out2s   = y1pad;

  // zero padded borders (whole buffers; interiors get overwritten)
  hipMemsetAsync(xpad1, 0, XPAD_B, stream);
  hipMemsetAsync(y1pad, 0, Y1PAD_B, stream);
  hipMemsetAsync(out1pad, 0, OUT1_B, stream);

  prep_x1<<<256, 256, 0, stream>>>(x, s1, xpad1);
  prep_w<<<1024, 256, 0, stream>>>(w1, wt1);
  prep_w<<<1024, 256, 0, stream>>>(w2, wt2);
  demod_k<<<dim3(512, 8, 2), 256, 0, stream>>>(w1, s1, d1, w2, s2, d2);

  // conv1: unfused convT (4 phases, 9 taps total) -> y1pad (raw * demod)
  gemm_conv<0><<<dim3(69, 4, 4), 256, 0, stream>>>(
      xpad1, wt1, d1, nullptr, nullptr, nullptr, nullptr, 0.f, y1pad);
  // blur + noise + bias + lrelu + s2-scale -> out1pad
  blur_noise_act<<<2048, 256, 0, stream>>>(y1pad, n1, nw1, b1, s2, out1pad);
  // conv2 (plain modulated conv) -> out2s (pre-scaled by srgb for ToRGB)
  gemm_conv<1><<<dim3(256, 4, 1), 256, 0, stream>>>(
      out1pad, wt2, d2, n2, nw2, b2, srgb, SCALE_RGB, out2s);
  // ToRGB + skip upsample
  torgb_skip<<<8192, 256, 0, stream>>>(out2s, wrgb, brgb, skip, (float*)d_out);
}

// Round 3
// 393.760 us; speedup vs baseline: 1.3407x; 1.0313x over previous
//
#include <hip/hip_runtime.h>
#include <stdint.h>

typedef unsigned short ushort_t;
typedef unsigned int uint_t;
typedef __bf16 bf16x8 __attribute__((ext_vector_type(8)));
typedef float f32x4 __attribute__((ext_vector_type(4)));

#define GLOBAL_AS __attribute__((address_space(1)))
#define LDS_AS    __attribute__((address_space(3)))

#define SCALE_CONV 0.014731391f   /* 1/sqrt(512*9) */
#define SCALE_RGB  0.044194174f   /* 1/sqrt(512)   */
#define SQRT2_F    1.41421356237f

// ---------------------------------------------------------------- helpers
__device__ __forceinline__ void async_cp16(const void* g, void* l) {
  __builtin_amdgcn_global_load_lds((const GLOBAL_AS uint_t*)g,
                                   (LDS_AS uint_t*)l, 16, 0, 0);
}
__device__ __forceinline__ ushort_t f2bf(float v) {
  union { float f; uint_t u; } c; c.f = v;
  uint_t r = c.u + 0x7fffu + ((c.u >> 16) & 1u);   // RNE
  return (ushort_t)(r >> 16);
}
__device__ __forceinline__ float bf2f(ushort_t u) {
  union { uint_t u; float f; } c; c.u = ((uint_t)u) << 16;
  return c.f;
}

// ------------------------------------------------- prep: x -> xpad1 (NHWC bf16, pad1, *s1*scale)
__global__ __launch_bounds__(256) void prep_x1(
    const float* __restrict__ x, const float* __restrict__ s1,
    ushort_t* __restrict__ xpad) {
  __shared__ ushort_t t[32 * 520];
  const int b  = blockIdx.x >> 5;
  const int j1 = blockIdx.x & 31;
  for (int idx = threadIdx.x; idx < 512 * 32; idx += 256) {
    int ci = idx >> 5, j2 = idx & 31;
    float v = x[(size_t)(b * 512 + ci) * 1024 + j1 * 32 + j2];
    v *= s1[b * 512 + ci] * SCALE_CONV;
    t[j2 * 520 + ci] = f2bf(v);
  }
  __syncthreads();
  for (int idx = threadIdx.x; idx < 32 * 512; idx += 256) {
    int j2 = idx >> 9, ci = idx & 511;
    xpad[((size_t)(b * 34 + j1 + 1) * 34 + (j2 + 1)) * 512 + ci] = t[j2 * 520 + ci];
  }
}

// ------------------------------------------------- prep: w1+w2 -> wt[plane][co][ci] bf16 + wsqT[ci][co]
__global__ __launch_bounds__(256) void prep_w(
    const float* __restrict__ w1, const float* __restrict__ w2,
    ushort_t* __restrict__ wt1, ushort_t* __restrict__ wt2,
    float* __restrict__ wsqT1, float* __restrict__ wsqT2) {
  int t = blockIdx.x * 256 + threadIdx.x;       // 2*512*512
  const float* w  = (t < 262144) ? w1 : w2;
  ushort_t*   wt  = (t < 262144) ? wt1 : wt2;
  float*      wq  = (t < 262144) ? wsqT1 : wsqT2;
  int tt = t & 262143;
  int ci = tt & 511, co = tt >> 9;
  const float* wp = w + (size_t)(co * 512 + ci) * 9;
  float sq = 0.f;
#pragma unroll
  for (int u = 0; u < 9; ++u) {
    float v = wp[u];
    sq += v * v;
    wt[((size_t)u * 512 + co) * 512 + ci] = f2bf(v);
  }
  wq[ci * 512 + co] = sq;
}

// ------------------------------------------------- demod: d[b][co] = rsqrt(scale^2 * sum_ci wsq*s^2 + eps)
__global__ __launch_bounds__(512) void demod2(
    const float* __restrict__ wsqT1, const float* __restrict__ s1, float* __restrict__ d1,
    const float* __restrict__ wsqT2, const float* __restrict__ s2, float* __restrict__ d2) {
  const float* wq = blockIdx.y ? wsqT2 : wsqT1;
  const float* s  = blockIdx.y ? s2 : s1;
  float*       d  = blockIdx.y ? d2 : d1;
  const int b  = blockIdx.x;
  const int co = threadIdx.x;
  __shared__ float ssq[512];
  float sv = s[b * 512 + co];
  ssq[co] = sv * sv;
  __syncthreads();
  float a = 0.f;
#pragma unroll 4
  for (int ci = 0; ci < 512; ++ci) a += wq[ci * 512 + co] * ssq[ci];
  d[b * 512 + co] = rsqrtf(a * (1.f / 4608.f) + 1e-8f);
}

// ------------------------------------------------- zero pad borders of the three padded buffers
__global__ __launch_bounds__(256) void border_zero(
    ushort_t* __restrict__ xpad, ushort_t* __restrict__ ypad, ushort_t* __restrict__ opad) {
  const int z = blockIdx.z;
  ushort_t* p = (z == 0) ? xpad : (z == 1 ? ypad : opad);
  const int W = (z == 0) ? 34 : (z == 1 ? 67 : 66);
  const int nb = 4 * W - 4;
  const int t = blockIdx.x * 256 + threadIdx.x;
  const int pix = t >> 6, ch = (t & 63) * 8;
  if (pix >= nb) return;
  const int b = blockIdx.y;
  int y, x;
  if (pix < W)          { y = 0;     x = pix; }
  else if (pix < 2 * W) { y = W - 1; x = pix - W; }
  else { int q = pix - 2 * W; y = 1 + (q >> 1); x = (q & 1) ? W - 1 : 0; }
  uint4 z4 = {0, 0, 0, 0};
  *(uint4*)(p + ((size_t)(b * W + y) * W + x) * 512 + ch) = z4;
}

// ------------------------------------------------- conv1 phase tap tables (convT stride-2, k=3)
__constant__ int           c_ph_off[4]  = {0, 4, 6, 8};
__constant__ int           c_ph_ntap[4] = {4, 2, 2, 1};
__constant__ unsigned char c_tap_u1[9]  = {0,0,1,1, 0,1, 1,1, 1};
__constant__ unsigned char c_tap_u2[9]  = {0,1,0,1, 1,1, 0,1, 1};
__constant__ unsigned char c_tap_pl[9]  = {8,6,2,0, 7,1, 5,3, 4};

// ------------------------------------------------- main implicit-GEMM conv, BK=64
// LDS layout: row r (0..127) x 8 chunks of 16B; chunk holding global k-quad c sits at
// position p=(c+r)&7 -> chunk-mod-8 distinct over every 8 consecutive lanes for both
// ds_read_b128 (rows consecutive per 8 lanes, same c) and staging. Staging lane l in an
// 8-row issue writes LDS chunk (l), i.e. global chunk ((l&7)-(l>>3))&7 of row base+(l>>3).
template <int MODE>
__global__ __launch_bounds__(256, 3) void gemm_conv(
    const ushort_t* __restrict__ inp, const ushort_t* __restrict__ wt,
    const float* __restrict__ dmod, const float* __restrict__ noise,
    const float* __restrict__ nw, const float* __restrict__ bias,
    const float* __restrict__ snext, float snext_scale,
    ushort_t* __restrict__ outp) {
  __shared__ ushort_t ldsA[128 * 64];
  __shared__ ushort_t ldsB[128 * 64];

  const int tid  = threadIdx.x;
  const int lane = tid & 63;
  const int wv   = tid >> 6;
  const int wm   = wv & 1;
  const int wn   = wv >> 1;
  const int l16  = lane & 15;
  const int quad = lane >> 4;

  const int mtile = blockIdx.x;
  const int ntile = blockIdx.y;
  const int a  = (MODE == 0) ? blockIdx.z : 0;
  const int a1 = a >> 1, a2 = a & 1;

  // ---- staging lane constants
  const int cl = ((lane & 7) - (lane >> 3)) & 7;   // global k-quad fetched by this lane
  const char* pA[4];
  const char* pB[4];
#pragma unroll
  for (int t = 0; t < 4; ++t) {
    int row = wv * 32 + t * 8 + (lane >> 3);
    int m   = mtile * 128 + row;
    size_t pix;
    if (MODE == 0) {
      if (m > 8711) m = 8711;
      int b = m / 1089, rr = m % 1089;
      int p1 = rr / 33, p2 = rr % 33;
      pix = ((size_t)(b * 34 + p1) * 34 + p2) * 512;
    } else {
      int b = m >> 12, o1 = (m >> 6) & 63, o2 = m & 63;
      pix = ((size_t)(b * 66 + o1 + 1) * 66 + (o2 + 1)) * 512;
    }
    pA[t] = (const char*)inp + pix * 2 + cl * 16;
    int n = ntile * 128 + row;
    pB[t] = (const char*)wt + (size_t)n * 1024 + cl * 16;
  }
  char* dstA[4];
  char* dstB[4];
#pragma unroll
  for (int t = 0; t < 4; ++t) {
    dstA[t] = (char*)ldsA + wv * 4096 + t * 1024;
    dstB[t] = (char*)ldsB + wv * 4096 + t * 1024;
  }

  // ---- MFMA fragment LDS offsets (ushort units); kk=1 chunk = kk=0 chunk ^ 32
  int offA[4], offB[4];
#pragma unroll
  for (int i = 0; i < 4; ++i) {
    int r  = wm * 64 + i * 16 + l16;
    int rn = wn * 64 + i * 16 + l16;
    offA[i] = r  * 64 + (((quad + r)  & 7) << 3);
    offB[i] = rn * 64 + (((quad + rn) & 7) << 3);
  }

  f32x4 acc[4][4];
#pragma unroll
  for (int i = 0; i < 4; ++i)
#pragma unroll
    for (int j = 0; j < 4; ++j) acc[i][j] = (f32x4){0.f, 0.f, 0.f, 0.f};

  const int ntap = (MODE == 0) ? c_ph_ntap[a] : 9;
#pragma unroll 1
  for (int ti = 0; ti < ntap; ++ti) {
    int aoff, boff;
    if (MODE == 0) {
      int e = c_ph_off[a] + ti;
      aoff = ((int)c_tap_u1[e] * 34 + (int)c_tap_u2[e]) * 1024;
      boff = (int)c_tap_pl[e] * 524288;
    } else {
      aoff = ((ti / 3 - 1) * 66 + (ti % 3 - 1)) * 1024;
      boff = ti * 524288;
    }
#pragma unroll 1
    for (int kc = 0; kc < 8; ++kc) {          // 512 ch / BK=64
      const int koff = kc * 128;
      __syncthreads();
#pragma unroll
      for (int t = 0; t < 4; ++t) async_cp16(pA[t] + aoff + koff, dstA[t]);
#pragma unroll
      for (int t = 0; t < 4; ++t) async_cp16(pB[t] + boff + koff, dstB[t]);
      __syncthreads();
#pragma unroll
      for (int kk = 0; kk < 2; ++kk) {
        const int kx = kk << 5;
        bf16x8 af[4], bg[4];
#pragma unroll
        for (int i = 0; i < 4; ++i) af[i] = *reinterpret_cast<const bf16x8*>(ldsA + (offA[i] ^ kx));
#pragma unroll
        for (int j = 0; j < 4; ++j) bg[j] = *reinterpret_cast<const bf16x8*>(ldsB + (offB[j] ^ kx));
#pragma unroll
        for (int i = 0; i < 4; ++i)
#pragma unroll
          for (int j = 0; j < 4; ++j)
            acc[i][j] = __builtin_amdgcn_mfma_f32_16x16x32_bf16(af[i], bg[j], acc[i][j], 0, 0, 0);
      }
    }
  }

  // ---- epilogue
  int co_[4];
#pragma unroll
  for (int j = 0; j < 4; ++j) co_[j] = ntile * 128 + wn * 64 + j * 16 + l16;

  if (MODE == 0) {
    // raw conv output * demod -> y1pad (blur/noise/act happen in the blur pass)
#pragma unroll
    for (int i = 0; i < 4; ++i) {
#pragma unroll
      for (int r = 0; r < 4; ++r) {
        int m = mtile * 128 + wm * 64 + i * 16 + quad * 4 + r;
        if (m < 8712) {
          int b = m / 1089, rr = m % 1089;
          int p1 = rr / 33, p2 = rr % 33;
          if ((a1 == 0 || p1 < 32) && (a2 == 0 || p2 < 32)) {
            int o1 = 2 * p1 + a1, o2 = 2 * p2 + a2;
            size_t ob = ((size_t)(b * 67 + o1 + 1) * 67 + (o2 + 1)) * 512;
#pragma unroll
            for (int j = 0; j < 4; ++j)
              outp[ob + co_[j]] = f2bf(acc[i][j][r] * dmod[b * 512 + co_[j]]);
          }
        }
      }
    }
  } else {
    const int b = mtile >> 5;
    const float nwv = nw[0];
    float dj_[4], sj_[4], bj_[4];
#pragma unroll
    for (int j = 0; j < 4; ++j) {
      dj_[j] = dmod[b * 512 + co_[j]];
      sj_[j] = snext[b * 512 + co_[j]] * snext_scale;
      bj_[j] = bias[co_[j]];
    }
#pragma unroll
    for (int i = 0; i < 4; ++i) {
#pragma unroll
      for (int r = 0; r < 4; ++r) {
        int m = mtile * 128 + wm * 64 + i * 16 + quad * 4 + r;
        int o1 = (m >> 6) & 63, o2 = m & 63;
        float nz = nwv * noise[(b << 12) + (o1 << 6) + o2];
        size_t ob = ((size_t)(b * 64 + o1) * 64 + o2) * 512;
#pragma unroll
        for (int j = 0; j < 4; ++j) {
          float v = acc[i][j][r] * dj_[j] + nz + bj_[j];
          v = (v >= 0.f ? v : 0.2f * v) * SQRT2_F;
          v *= sj_[j];
          outp[ob + co_[j]] = f2bf(v);
        }
      }
    }
  }
}

// ------------------------------------------------- blur(4-tap separable) + noise + bias + lrelu + s2-scale
__global__ __launch_bounds__(256) void blur_noise_act(
    const ushort_t* __restrict__ y1pad, const float* __restrict__ noise,
    const float* __restrict__ nw, const float* __restrict__ bias,
    const float* __restrict__ s2, ushort_t* __restrict__ out1pad) {
  const int cg  = threadIdx.x & 63;                       // channel octet
  const int pg  = blockIdx.x * 4 + (threadIdx.x >> 6);    // 0..8191
  const int b   = pg >> 10;
  const int q1  = (pg >> 4) & 63;
  const int q2g = (pg & 15) * 4;                          // 4 consecutive output cols
  const float cw[4] = {0.25f, 0.75f, 0.75f, 0.25f};

  float acc[4][8];
#pragma unroll
  for (int j = 0; j < 4; ++j)
#pragma unroll
    for (int e = 0; e < 8; ++e) acc[j][e] = 0.f;

#pragma unroll
  for (int t2 = 0; t2 < 7; ++t2) {
    int cc = q2g + t2;
    float vt[8];
#pragma unroll
    for (int e = 0; e < 8; ++e) vt[e] = 0.f;
#pragma unroll
    for (int t1 = 0; t1 < 4; ++t1) {
      const ushort_t* p = y1pad + ((size_t)(b * 67 + q1 + t1) * 67 + cc) * 512 + cg * 8;
      ushort_t v[8];
      *(uint4*)v = *(const uint4*)p;
#pragma unroll
      for (int e = 0; e < 8; ++e) vt[e] += cw[t1] * bf2f(v[e]);
    }
#pragma unroll
    for (int j = 0; j < 4; ++j) {
      int t = t2 - j;
      if (t >= 0 && t < 4) {
#pragma unroll
        for (int e = 0; e < 8; ++e) acc[j][e] += cw[t] * vt[e];
      }
    }
  }

  const float nwv = nw[0];
  float bj[8], sj[8];
#pragma unroll
  for (int e = 0; e < 8; ++e) {
    bj[e] = bias[cg * 8 + e];
    sj[e] = s2[b * 512 + cg * 8 + e] * SCALE_CONV;
  }
#pragma unroll
  for (int j = 0; j < 4; ++j) {
    int q2 = q2g + j;
    float nz = nwv * noise[(b << 12) + (q1 << 6) + q2];
    ushort_t o[8];
#pragma unroll
    for (int e = 0; e < 8; ++e) {
      float v = acc[j][e] + nz + bj[e];
      v = (v >= 0.f ? v : 0.2f * v) * SQRT2_F * sj[e];
      o[e] = f2bf(v);
    }
    *(uint4*)(out1pad + ((size_t)(b * 66 + q1 + 1) * 66 + (q2 + 1)) * 512 + cg * 8) = *(uint4*)o;
  }
}

// ------------------------------------------------- ToRGB (1x1, no demod) + bias + skip upfirdn(up=2)
__global__ __launch_bounds__(256) void torgb_skip(
    const ushort_t* __restrict__ out2s, const float* __restrict__ wrgb,
    const float* __restrict__ brgb, const float* __restrict__ skip,
    float* __restrict__ out) {
  const int lane = threadIdx.x & 63;
  const int pix  = blockIdx.x * 4 + (threadIdx.x >> 6);   // 32768 pixels
  const int b = pix >> 12, o1 = (pix >> 6) & 63, o2 = pix & 63;
  const ushort_t* src = out2s + (size_t)pix * 512 + lane * 8;
  ushort_t v[8];
  *(uint4*)v = *(const uint4*)src;
  float s0 = 0.f, s1 = 0.f, s2 = 0.f;
#pragma unroll
  for (int e = 0; e < 8; ++e) {
    float xv = bf2f(v[e]);
    int ci = lane * 8 + e;
    s0 += xv * wrgb[ci];
    s1 += xv * wrgb[512 + ci];
    s2 += xv * wrgb[1024 + ci];
  }
#pragma unroll
  for (int o = 32; o; o >>= 1) {
    s0 += __shfl_xor(s0, o);
    s1 += __shfl_xor(s1, o);
    s2 += __shfl_xor(s2, o);
  }
  if (lane < 3) {
    float v3 = (lane == 0) ? s0 : (lane == 1 ? s1 : s2);
    int P1 = o1 >> 1, P2 = o2 >> 1;
    int jy0, jy1, jx0, jx1;
    float wy0, wy1, wx0, wx1;
    if ((o1 & 1) == 0) { jy0 = P1 - 1; wy0 = .25f; jy1 = P1;     wy1 = .75f; }
    else               { jy0 = P1;     wy0 = .75f; jy1 = P1 + 1; wy1 = .25f; }
    if ((o2 & 1) == 0) { jx0 = P2 - 1; wx0 = .25f; jx1 = P2;     wx1 = .75f; }
    else               { jx0 = P2;     wx0 = .75f; jx1 = P2 + 1; wx1 = .25f; }
    const float* sp = skip + (size_t)(b * 3 + lane) * 1024;
    float sv = 0.f;
    if (jy0 >= 0 && jy0 < 32) {
      if (jx0 >= 0 && jx0 < 32) sv += wy0 * wx0 * sp[jy0 * 32 + jx0];
      if (jx1 >= 0 && jx1 < 32) sv += wy0 * wx1 * sp[jy0 * 32 + jx1];
    }
    if (jy1 >= 0 && jy1 < 32) {
      if (jx0 >= 0 && jx0 < 32) sv += wy1 * wx0 * sp[jy1 * 32 + jx0];
      if (jx1 >= 0 && jx1 < 32) sv += wy1 * wx1 * sp[jy1 * 32 + jx1];
    }
    out[((size_t)(b * 3 + lane) << 12) + (o1 << 6) + o2] = v3 + brgb[lane] + sv;
  }
}

// ------------------------------------------------- launch
extern "C" void kernel_launch(void* const* d_in, const int* in_sizes, int n_in,
                              void* d_out, int out_size, void* d_ws, size_t ws_size,
                              hipStream_t stream) {
  const float* x    = (const float*)d_in[0];
  const float* skip = (const float*)d_in[1];
  const float* w1   = (const float*)d_in[2];
  const float* b1   = (const float*)d_in[3];
  const float* s1   = (const float*)d_in[4];
  const float* nw1  = (const float*)d_in[5];
  const float* n1   = (const float*)d_in[6];
  const float* w2   = (const float*)d_in[7];
  const float* b2   = (const float*)d_in[8];
  const float* s2   = (const float*)d_in[9];
  const float* nw2  = (const float*)d_in[10];
  const float* n2   = (const float*)d_in[11];
  const float* wrgb = (const float*)d_in[12];
  const float* brgb = (const float*)d_in[13];
  const float* srgb = (const float*)d_in[14];

  char* ws = (char*)d_ws;
  const size_t XPAD_B  = (size_t)8 * 34 * 34 * 512 * 2;   //  9,469,952
  const size_t Y1PAD_B = (size_t)8 * 67 * 67 * 512 * 2;   // 36,773,888
  const size_t OUT1_B  = (size_t)8 * 66 * 66 * 512 * 2;   // 35,684,352
  const size_t WT_B    = (size_t)9 * 512 * 512 * 2;       //  4,718,592
  size_t off = 0;
  ushort_t* xpad1   = (ushort_t*)(ws + off); off += XPAD_B;
  ushort_t* y1pad   = (ushort_t*)(ws + off); off += Y1PAD_B;
  ushort_t* out1pad = (ushort_t*)(ws + off); off += OUT1_B;
  ushort_t* wt1     = (ushort_t*)(ws + off); off += WT_B;
  ushort_t* wt2     = (ushort_t*)(ws + off); off += WT_B;
  float*    d1      = (float*)(ws + off);    off += 8 * 512 * 4;
  float*    d2      = (float*)(ws + off);    off += 8 * 512 * 4;
  // out2s aliases y1pad (dead after blur); wsqT1/2 alias y1pad (consumed by demod2 before
  // border_zero/gemm touch y1pad)
  ushort_t* out2s  = y1pad;
  float*    wsqT1  = (float*)y1pad;
  float*    wsqT2  = wsqT1 + 512 * 512;

  prep_x1<<<256, 256, 0, stream>>>(x, s1, xpad1);
  prep_w<<<2048, 256, 0, stream>>>(w1, w2, wt1, wt2, wsqT1, wsqT2);
  demod2<<<dim3(8, 2), 512, 0, stream>>>(wsqT1, s1, d1, wsqT2, s2, d2);
  border_zero<<<dim3(66, 8, 3), 256, 0, stream>>>(xpad1, y1pad, out1pad);

  // conv1: unfused convT (4 phases, 9 taps total) -> y1pad (raw * demod)
  gemm_conv<0><<<dim3(69, 4, 4), 256, 0, stream>>>(
      xpad1, wt1, d1, nullptr, nullptr, nullptr, nullptr, 0.f, y1pad);
  // blur + noise + bias + lrelu + s2-scale -> out1pad
  blur_noise_act<<<2048, 256, 0, stream>>>(y1pad, n1, nw1, b1, s2, out1pad);
  // conv2 (plain modulated conv) -> out2s (pre-scaled by srgb for ToRGB)
  gemm_conv<1><<<dim3(256, 4, 1), 256, 0, stream>>>(
      out1pad, wt2, d2, n2, nw2, b2, srgb, SCALE_RGB, out2s);
  // ToRGB + skip upsample
  torgb_skip<<<8192, 256, 0, stream>>>(out2s, wrgb, brgb, skip, (float*)d_out);
}